// Round 18
// baseline (108.582 us; speedup 1.0000x reference)
//
#include <hip/hip_runtime.h>

#define TSD 512      // TS (feature dim)
#define SRC 256
#define TGT 256
#define NB  4        // batch
#define KSCALE 2.885390081777927f       // 2*log2(e): exp2(K*x) == exp(2x)
#define SCALE  9.5367431640625e-07f     // 2^-20: overflow headroom for 4-way product
#define EPSV   1e-20f

// ---------------------------------------------------------------------------
// W transpose: Wt[d][o] = W[o][d]  (W: 512 x 1024 -> Wt: 1024 x 512).
// Wt[z*512 + k][o] is the B-operand [k][o] for GEMM z. (R16-proven.)
// ---------------------------------------------------------------------------
__global__ __launch_bounds__(256) void transpose_w_kernel(
    const float* __restrict__ W, float* __restrict__ Wt)
{
    __shared__ float t[32][33];
    const int tid = threadIdx.x;
    const int d0 = blockIdx.x * 32;
    const int o0 = blockIdx.y * 32;
    const int r  = tid >> 3;          // 0..31
    const int c4 = (tid & 7) * 4;     // 0..28

    const float4 w4 = *reinterpret_cast<const float4*>(
        &W[(size_t)(o0 + r) * 1024 + d0 + c4]);
    t[r][c4 + 0] = w4.x; t[r][c4 + 1] = w4.y;
    t[r][c4 + 2] = w4.z; t[r][c4 + 3] = w4.w;
    __syncthreads();

    float4 out;
    out.x = t[c4 + 0][r]; out.y = t[c4 + 1][r];
    out.z = t[c4 + 2][r]; out.w = t[c4 + 3][r];
    *reinterpret_cast<float4*>(&Wt[(size_t)(d0 + r) * TSD + o0 + c4]) = out;
}

// ---------------------------------------------------------------------------
// Projection GEMM, SGPR-B scheme: thread owns ONE row (256 rows/block) and a
// block-uniform 16-col tile. Per k: 1 conflict-free ds_read_b32 (A) + 16 fma
// with B from SGPRs (s_load, scalar pipe). fma:LDS-dword = 16:1.
// Grid (TSD/16=32, 1024/256=4, 2) = 256 blocks, 256 thr.
// z=0: hpE2[r][o]   = S * exp2(K*(hid.Wh)[r][o]) / v[o]       (row-major)
// z=1: epE[b][o][s] = exp2(K*((enc.We)[r][o] + bias[o]))      (TRANSPOSED,
//      naturally coalesced here: lane = s)
// ---------------------------------------------------------------------------
__global__ __launch_bounds__(256) void proj_kernel(
    const float* __restrict__ hid, const float* __restrict__ enc,
    const float* __restrict__ Wt, const float* __restrict__ bias,
    const float* __restrict__ v,
    float* __restrict__ hpE2, float* __restrict__ epE)
{
    const int z = blockIdx.z;
    const float* __restrict__ X  = z ? enc : hid;
    const float* __restrict__ Bt = Wt + (size_t)z * TSD * TSD;   // [k][o]

    __shared__ float Xs[16][258];   // [k][r], pad 258 -> conflict-free b32

    const int tid = threadIdx.x;
    const int c0 = blockIdx.x * 16;     // col tile (block-uniform)
    const int r0 = blockIdx.y * 256;    // row block (within z)

    float acc[16] = {};

    for (int k0 = 0; k0 < TSD; k0 += 16) {
        __syncthreads();
        // stage 256 rows x 16 k (coalesced float4 reads, 2-way-max bank writes)
        #pragma unroll
        for (int rq = 0; rq < 4; ++rq) {
            const int m  = (tid >> 2) + rq * 64;
            const int kq = (tid & 3) * 4;
            const float4 a = *reinterpret_cast<const float4*>(
                &X[(size_t)(r0 + m) * TSD + k0 + kq]);
            Xs[kq + 0][m] = a.x; Xs[kq + 1][m] = a.y;
            Xs[kq + 2][m] = a.z; Xs[kq + 3][m] = a.w;
        }
        __syncthreads();
        #pragma unroll
        for (int k = 0; k < 16; ++k) {
            // B row k0+k, cols c0..c0+15: block-uniform -> s_load (scalar pipe)
            const float* __restrict__ brow = &Bt[(size_t)(k0 + k) * TSD + c0];
            float b[16];
            #pragma unroll
            for (int j = 0; j < 16; ++j) b[j] = brow[j];
            const float a = Xs[k][tid];          // conflict-free b32
            #pragma unroll
            for (int j = 0; j < 16; ++j)
                acc[j] = fmaf(a, b[j], acc[j]);  // VGPR x SGPR + VGPR
        }
    }

    if (z) {
        // epE[b][o][s] = exp2(K*(C+bias[o])); rows of this block = one batch,
        // s = tid -> consecutive lanes, coalesced store per j.
        const int b = r0 >> 8;
        #pragma unroll
        for (int j = 0; j < 16; ++j) {
            const float bj = bias[c0 + j];       // uniform
            const float val = __builtin_amdgcn_exp2f((acc[j] + bj) * KSCALE);
            epE[((size_t)b * TSD + c0 + j) * SRC + tid] = val;
        }
    } else {
        // hpE2[r][o] = S*exp2(K*C)/v[o]; thread writes its row's 16 cols.
        float iv[16];
        #pragma unroll
        for (int j = 0; j < 16; ++j)
            iv[j] = SCALE * __builtin_amdgcn_rcpf(fmaxf(v[c0 + j], EPSV));  // uniform
        const size_t base = (size_t)(r0 + tid) * TSD + c0;
        #pragma unroll
        for (int q = 0; q < 4; ++q) {
            float4 o4;
            o4.x = __builtin_amdgcn_exp2f(acc[q * 4 + 0] * KSCALE) * iv[q * 4 + 0];
            o4.y = __builtin_amdgcn_exp2f(acc[q * 4 + 1] * KSCALE) * iv[q * 4 + 1];
            o4.z = __builtin_amdgcn_exp2f(acc[q * 4 + 2] * KSCALE) * iv[q * 4 + 2];
            o4.w = __builtin_amdgcn_exp2f(acc[q * 4 + 3] * KSCALE) * iv[q * 4 + 3];
            *reinterpret_cast<float4*>(&hpE2[base + q * 4]) = o4;
        }
    }
}

__device__ __forceinline__ float wave_red_sum(float v) {
    #pragma unroll
    for (int off = 1; off < 64; off <<= 1) v += __shfl_xor(v, off, 64);
    return v;
}
__device__ __forceinline__ float wave_red_max(float v) {
    #pragma unroll
    for (int off = 1; off < 64; off <<= 1) v = fmaxf(v, __shfl_xor(v, off, 64));
    return v;
}

// 4 t-rows at one s: w_t = eh_t*ee + iv (one fma each); 4 terms share one rcp
#define GRP4(EH, EE, IV, A0, A1, A2, A3) {                        \
    const float w0_ = fmaf((EH).x, (EE), IV);                     \
    const float w1_ = fmaf((EH).y, (EE), IV);                     \
    const float w2_ = fmaf((EH).z, (EE), IV);                     \
    const float w3_ = fmaf((EH).w, (EE), IV);                     \
    const float p01_ = w0_ * w1_;                                 \
    const float p23_ = w2_ * w3_;                                 \
    const float r_   = __builtin_amdgcn_rcpf(p01_ * p23_);        \
    const float rp01_ = r_ * p01_;                                \
    const float rp23_ = r_ * p23_;                                \
    A0 = fmaf(rp23_, w1_, A0); A1 = fmaf(rp23_, w0_, A1);         \
    A2 = fmaf(rp01_, w3_, A2); A3 = fmaf(rp01_, w2_, A3); }

// ---------------------------------------------------------------------------
// Fused score + softmax + context (R13-proven, unchanged).
// Grid (TGT/4, NB), 1024 thr = 16 waves; wave: s-half = w>>3, o-slice = w&7.
// ---------------------------------------------------------------------------
__global__ __launch_bounds__(1024) void attn_fused_kernel(
    const float* __restrict__ hpE2, const float* __restrict__ epE,
    const float* __restrict__ v, const int* __restrict__ mask,
    const float* __restrict__ enc,
    float* __restrict__ ctx_out, float* __restrict__ probs_out)
{
    __shared__ float4 eh4[TSD];       // Eh2s packed by t       (8 KB)
    __shared__ float  ivs[TSD];       // S/v[o]                 (2 KB)
    __shared__ float  red8[8][SRC];   // o-slice partials       (8 KB, reused per t)
    __shared__ float  Plds[4][SRC];   // P, then probs          (4 KB)
    __shared__ float  redgA[4][4];
    __shared__ float  redgB[4][4];

    const int tid = threadIdx.x;
    const int b  = blockIdx.y;
    const int t0 = blockIdx.x * 4;

    // ---- stage Eh2s (4 rows packed per o) + ivs ----
    if (tid < 512) {
        const int row = tid >> 7;            // 0..3
        const int oq  = (tid & 127) * 4;
        const float4 hh = *reinterpret_cast<const float4*>(
            &hpE2[((size_t)(b * TGT + t0 + row)) * TSD + oq]);
        ((float*)&eh4[oq + 0])[row] = hh.x;
        ((float*)&eh4[oq + 1])[row] = hh.y;
        ((float*)&eh4[oq + 2])[row] = hh.z;
        ((float*)&eh4[oq + 3])[row] = hh.w;
    } else {
        const int o = tid - 512;
        ivs[o] = SCALE * __builtin_amdgcn_rcpf(fmaxf(v[o], EPSV));
    }
    __syncthreads();

    // ---- score partials ----
    const int w    = __builtin_amdgcn_readfirstlane(tid >> 6);  // wave 0..15
    const int lane = tid & 63;
    const int sh   = w >> 3;                                    // s-half
    const int ow   = w & 7;                                     // o-slice
    const int obase = ow * 64;
    const float* __restrict__ epb =
        epE + (size_t)b * TSD * SRC + (size_t)obase * SRC + sh * 128 + 2 * lane;

    float acc[4][2] = {};   // [t][s-sub]
    #pragma unroll 4
    for (int oi = 0; oi < 64; ++oi) {
        const int o = obase + oi;
        const float2 ee = *reinterpret_cast<const float2*>(epb + (size_t)oi * SRC);
        const float4 eh = eh4[o];       // uniform -> ds_read_b128 broadcast
        const float  iv = ivs[o];       // uniform -> ds_read_b32 broadcast
        GRP4(eh, ee.x, iv, acc[0][0], acc[1][0], acc[2][0], acc[3][0])
        GRP4(eh, ee.y, iv, acc[0][1], acc[1][1], acc[2][1], acc[3][1])
    }

    // ---- combine 8 o-slices per t (red8 reused across t) ----
    #pragma unroll
    for (int t = 0; t < 4; ++t) {
        __syncthreads();
        float2 r2; r2.x = acc[t][0]; r2.y = acc[t][1];
        *reinterpret_cast<float2*>(&red8[ow][sh * 128 + 2 * lane]) = r2;
        __syncthreads();
        if (tid < SRC) {
            float Ps = 0.f;
            #pragma unroll
            for (int r = 0; r < 8; ++r) Ps += red8[r][tid];
            Plds[t][tid] = Ps * SCALE;
        }
    }
    __syncthreads();

    // ---- softmax: group g = tid>>8 handles row t0+g, s = tid&255 ----
    const int g = __builtin_amdgcn_readfirstlane(tid >> 8);
    const int s = tid & 255;
    const int wig = (tid >> 6) & 3;

    float sv = v[s] + v[s + 256];
    {
        float wsv = wave_red_sum(sv);
        if ((tid & 63) == 0) redgA[g][wig] = wsv;
    }
    __syncthreads();
    const float sumv = redgA[g][0] + redgA[g][1] + redgA[g][2] + redgA[g][3];
    const float score = sumv - 2.f * Plds[g][s];

    {
        float wm = wave_red_max(score);
        if ((tid & 63) == 0) redgB[g][wig] = wm;
    }
    __syncthreads();
    const float mx = fmaxf(fmaxf(redgB[g][0], redgB[g][1]), fmaxf(redgB[g][2], redgB[g][3]));
    const float e = __expf(score - mx);
    {
        float ws = wave_red_sum(e);
        if ((tid & 63) == 0) redgA[g][wig] = ws;
    }
    __syncthreads();
    const float sE = redgA[g][0] + redgA[g][1] + redgA[g][2] + redgA[g][3];
    const float mq = (e / sE) * (float)mask[b * SRC + s];
    {
        float ws = wave_red_sum(mq);
        if ((tid & 63) == 0) redgB[g][wig] = ws;
    }
    __syncthreads();
    const float sM = redgB[g][0] + redgB[g][1] + redgB[g][2] + redgB[g][3];
    const float p = mq / (sM + 1e-12f);
    __syncthreads();
    Plds[g][s] = p;
    probs_out[((size_t)(b * TGT + t0 + g)) * SRC + s] = p;
    __syncthreads();

    // ---- context: dg = tid>>9 handles rows {2dg, 2dg+1}; d = tid&511 ----
    const int dg = tid >> 9;
    const int d  = tid & 511;
    const float* __restrict__ encb = enc + (size_t)b * SRC * TSD + d;
    float c0 = 0.f, c1 = 0.f;
    #pragma unroll 4
    for (int s2 = 0; s2 < SRC; ++s2) {
        const float ev = encb[(size_t)s2 * TSD];
        c0 = fmaf(Plds[2 * dg + 0][s2], ev, c0);
        c1 = fmaf(Plds[2 * dg + 1][s2], ev, c1);
    }
    ctx_out[((size_t)(b * TGT + t0 + 2 * dg + 0)) * TSD + d] = c0;
    ctx_out[((size_t)(b * TGT + t0 + 2 * dg + 1)) * TSD + d] = c1;
}

extern "C" void kernel_launch(void* const* d_in, const int* in_sizes, int n_in,
                              void* d_out, int out_size, void* d_ws, size_t ws_size,
                              hipStream_t stream) {
    const float* hid  = (const float*)d_in[0];   // (4,256,512)
    const float* enc  = (const float*)d_in[1];   // (4,256,512)
    const int*   mask = (const int*)  d_in[2];   // (4,256)
    const float* W    = (const float*)d_in[3];   // (512,1024)
    const float* bias = (const float*)d_in[4];   // (512,)
    const float* v    = (const float*)d_in[5];   // (512,)

    float* out   = (float*)d_out;
    float* ctx   = out;                       // 4*256*512
    float* probs = out + NB * TGT * TSD;      // 4*256*256

    float* hpE2 = (float*)d_ws;               // 1024*512: S*exp2(K*h)/v    2 MB
    float* epE  = hpE2 + NB * TGT * TSD;      // 4*512*256: exp2(K*(e+b))^T 2 MB
    float* Wt   = epE + NB * TSD * SRC;       // 1024*512: W transposed     2 MB

    transpose_w_kernel<<<dim3(1024 / 32, TSD / 32), 256, 0, stream>>>(W, Wt);

    dim3 pg(TSD / 16, 1024 / 256, 2);
    proj_kernel<<<pg, 256, 0, stream>>>(hid, enc, Wt, bias, v, hpE2, epE);

    dim3 ag(TGT / 4, NB);
    attn_fused_kernel<<<ag, 1024, 0, stream>>>(hpE2, epE, v, mask, enc, ctx, probs);
}

// Round 19
// 66.212 us; speedup vs baseline: 1.6399x; 1.6399x over previous
//
#include <hip/hip_runtime.h>

#define TSD 512      // TS (feature dim)
#define SRC 256
#define TGT 256
#define NB  4        // batch
#define KSCALE 2.885390081777927f       // 2*log2(e): exp2(K*x) == exp(2x)
#define SCALE  9.5367431640625e-07f     // 2^-20: overflow headroom for 4-way product
#define EPSV   1e-20f

// ---------------------------------------------------------------------------
// Projection GEMM (R9-proven): 64x64 tiles, 4x4 micro-tile, BK=16.
// z=0: hpE2[r][o]   = S * exp2(K*(hid.Wh)[r][o]) / v[o]       (row-major)
// z=1: epE[b][o][s] = exp2(K*((enc.We)[r][o] + bias[o]))      (TRANSPOSED)
// ---------------------------------------------------------------------------
__global__ __launch_bounds__(256) void proj_kernel(
    const float* __restrict__ hid, const float* __restrict__ enc,
    const float* __restrict__ W, const float* __restrict__ bias,
    const float* __restrict__ v,
    float* __restrict__ hpE2, float* __restrict__ epE)
{
    const int z = blockIdx.z;
    const float* __restrict__ X = z ? enc : hid;
    const int wofs = z ? TSD : 0;

    __shared__ float Xs[16][68];   // [k][m]
    __shared__ float Ws[16][68];   // [k][n]
    __shared__ float tile[64][68]; // transpose staging (z=1)

    const int tx = threadIdx.x, ty = threadIdx.y;
    const int tid = ty * 16 + tx;
    const int o0 = blockIdx.x * 64;
    const int r0 = blockIdx.y * 64;

    const int m  = tid >> 2;        // 0..63
    const int kq = (tid & 3) * 4;   // 0,4,8,12

    float acc[4][4] = {};

    for (int k0 = 0; k0 < TSD; k0 += 16) {
        __syncthreads();
        float4 av = *reinterpret_cast<const float4*>(&X[(r0 + m) * TSD + k0 + kq]);
        float4 wv = *reinterpret_cast<const float4*>(&W[(o0 + m) * (2 * TSD) + wofs + k0 + kq]);
        Xs[kq + 0][m] = av.x; Xs[kq + 1][m] = av.y; Xs[kq + 2][m] = av.z; Xs[kq + 3][m] = av.w;
        Ws[kq + 0][m] = wv.x; Ws[kq + 1][m] = wv.y; Ws[kq + 2][m] = wv.z; Ws[kq + 3][m] = wv.w;
        __syncthreads();
        #pragma unroll
        for (int k = 0; k < 16; ++k) {
            float4 a  = *reinterpret_cast<const float4*>(&Xs[k][ty * 4]);
            float4 bb = *reinterpret_cast<const float4*>(&Ws[k][tx * 4]);
            float ar[4] = {a.x, a.y, a.z, a.w};
            float br[4] = {bb.x, bb.y, bb.z, bb.w};
            #pragma unroll
            for (int i = 0; i < 4; ++i)
                #pragma unroll
                for (int j = 0; j < 4; ++j)
                    acc[i][j] = fmaf(ar[i], br[j], acc[i][j]);
        }
    }

    if (z) {
        const float b0 = bias[o0 + tx * 4 + 0];
        const float b1 = bias[o0 + tx * 4 + 1];
        const float b2 = bias[o0 + tx * 4 + 2];
        const float b3 = bias[o0 + tx * 4 + 3];
        __syncthreads();
        #pragma unroll
        for (int i = 0; i < 4; ++i) {
            float4 val;
            val.x = __builtin_amdgcn_exp2f((acc[i][0] + b0) * KSCALE);
            val.y = __builtin_amdgcn_exp2f((acc[i][1] + b1) * KSCALE);
            val.z = __builtin_amdgcn_exp2f((acc[i][2] + b2) * KSCALE);
            val.w = __builtin_amdgcn_exp2f((acc[i][3] + b3) * KSCALE);
            *reinterpret_cast<float4*>(&tile[ty * 4 + i][tx * 4]) = val;
        }
        __syncthreads();
        const int bb_ = r0 >> 8;
        const int s0  = (r0 & 255) + (tid & 15) * 4;
        #pragma unroll
        for (int it = 0; it < 4; ++it) {
            const int ol = it * 16 + (tid >> 4);
            float4 val;
            val.x = tile[(tid & 15) * 4 + 0][ol];
            val.y = tile[(tid & 15) * 4 + 1][ol];
            val.z = tile[(tid & 15) * 4 + 2][ol];
            val.w = tile[(tid & 15) * 4 + 3][ol];
            *reinterpret_cast<float4*>(&epE[((size_t)bb_ * TSD + o0 + ol) * SRC + s0]) = val;
        }
    } else {
        const int oc = o0 + tx * 4;
        float iv[4];
        #pragma unroll
        for (int j = 0; j < 4; ++j)
            iv[j] = SCALE * __builtin_amdgcn_rcpf(fmaxf(v[oc + j], EPSV));
        #pragma unroll
        for (int i = 0; i < 4; ++i) {
            const int r = r0 + ty * 4 + i;
            float4 o4;
            o4.x = __builtin_amdgcn_exp2f(acc[i][0] * KSCALE) * iv[0];
            o4.y = __builtin_amdgcn_exp2f(acc[i][1] * KSCALE) * iv[1];
            o4.z = __builtin_amdgcn_exp2f(acc[i][2] * KSCALE) * iv[2];
            o4.w = __builtin_amdgcn_exp2f(acc[i][3] * KSCALE) * iv[3];
            *reinterpret_cast<float4*>(&hpE2[r * TSD + oc]) = o4;
        }
    }
}

__device__ __forceinline__ float wave_red_sum(float v) {
    #pragma unroll
    for (int off = 1; off < 64; off <<= 1) v += __shfl_xor(v, off, 64);
    return v;
}
__device__ __forceinline__ float wave_red_max(float v) {
    #pragma unroll
    for (int off = 1; off < 64; off <<= 1) v = fmaxf(v, __shfl_xor(v, off, 64));
    return v;
}

// 4 t-rows at one s: w_t = eh_t*ee + iv (one fma each); 4 terms share one rcp
#define GRP4(EH, EE, IV, A0, A1, A2, A3) {                        \
    const float w0_ = fmaf((EH).x, (EE), IV);                     \
    const float w1_ = fmaf((EH).y, (EE), IV);                     \
    const float w2_ = fmaf((EH).z, (EE), IV);                     \
    const float w3_ = fmaf((EH).w, (EE), IV);                     \
    const float p01_ = w0_ * w1_;                                 \
    const float p23_ = w2_ * w3_;                                 \
    const float r_   = __builtin_amdgcn_rcpf(p01_ * p23_);        \
    const float rp01_ = r_ * p01_;                                \
    const float rp23_ = r_ * p23_;                                \
    A0 = fmaf(rp23_, w1_, A0); A1 = fmaf(rp23_, w0_, A1);         \
    A2 = fmaf(rp01_, w3_, A2); A3 = fmaf(rp01_, w2_, A3); }

// ---------------------------------------------------------------------------
// Fused score + softmax + context (R13-proven, unchanged).
// Grid (TGT/4, NB), 1024 thr = 16 waves; wave: s-half = w>>3, o-slice = w&7.
// ---------------------------------------------------------------------------
__global__ __launch_bounds__(1024) void attn_fused_kernel(
    const float* __restrict__ hpE2, const float* __restrict__ epE,
    const float* __restrict__ v, const int* __restrict__ mask,
    const float* __restrict__ enc,
    float* __restrict__ ctx_out, float* __restrict__ probs_out)
{
    __shared__ float4 eh4[TSD];       // Eh2s packed by t       (8 KB)
    __shared__ float  ivs[TSD];       // S/v[o]                 (2 KB)
    __shared__ float  red8[8][SRC];   // o-slice partials       (8 KB, reused per t)
    __shared__ float  Plds[4][SRC];   // P, then probs          (4 KB)
    __shared__ float  redgA[4][4];
    __shared__ float  redgB[4][4];

    const int tid = threadIdx.x;
    const int b  = blockIdx.y;
    const int t0 = blockIdx.x * 4;

    // ---- stage Eh2s (4 rows packed per o) + ivs ----
    if (tid < 512) {
        const int row = tid >> 7;            // 0..3
        const int oq  = (tid & 127) * 4;
        const float4 hh = *reinterpret_cast<const float4*>(
            &hpE2[((size_t)(b * TGT + t0 + row)) * TSD + oq]);
        ((float*)&eh4[oq + 0])[row] = hh.x;
        ((float*)&eh4[oq + 1])[row] = hh.y;
        ((float*)&eh4[oq + 2])[row] = hh.z;
        ((float*)&eh4[oq + 3])[row] = hh.w;
    } else {
        const int o = tid - 512;
        ivs[o] = SCALE * __builtin_amdgcn_rcpf(fmaxf(v[o], EPSV));
    }
    __syncthreads();

    // ---- score partials ----
    const int w    = __builtin_amdgcn_readfirstlane(tid >> 6);  // wave 0..15
    const int lane = tid & 63;
    const int sh   = w >> 3;                                    // s-half
    const int ow   = w & 7;                                     // o-slice
    const int obase = ow * 64;
    const float* __restrict__ epb =
        epE + (size_t)b * TSD * SRC + (size_t)obase * SRC + sh * 128 + 2 * lane;

    float acc[4][2] = {};   // [t][s-sub]
    #pragma unroll 4
    for (int oi = 0; oi < 64; ++oi) {
        const int o = obase + oi;
        const float2 ee = *reinterpret_cast<const float2*>(epb + (size_t)oi * SRC);
        const float4 eh = eh4[o];       // uniform -> ds_read_b128 broadcast
        const float  iv = ivs[o];       // uniform -> ds_read_b32 broadcast
        GRP4(eh, ee.x, iv, acc[0][0], acc[1][0], acc[2][0], acc[3][0])
        GRP4(eh, ee.y, iv, acc[0][1], acc[1][1], acc[2][1], acc[3][1])
    }

    // ---- combine 8 o-slices per t (red8 reused across t) ----
    #pragma unroll
    for (int t = 0; t < 4; ++t) {
        __syncthreads();
        float2 r2; r2.x = acc[t][0]; r2.y = acc[t][1];
        *reinterpret_cast<float2*>(&red8[ow][sh * 128 + 2 * lane]) = r2;
        __syncthreads();
        if (tid < SRC) {
            float Ps = 0.f;
            #pragma unroll
            for (int r = 0; r < 8; ++r) Ps += red8[r][tid];
            Plds[t][tid] = Ps * SCALE;
        }
    }
    __syncthreads();

    // ---- softmax: group g = tid>>8 handles row t0+g, s = tid&255 ----
    const int g = __builtin_amdgcn_readfirstlane(tid >> 8);
    const int s = tid & 255;
    const int wig = (tid >> 6) & 3;

    float sv = v[s] + v[s + 256];
    {
        float wsv = wave_red_sum(sv);
        if ((tid & 63) == 0) redgA[g][wig] = wsv;
    }
    __syncthreads();
    const float sumv = redgA[g][0] + redgA[g][1] + redgA[g][2] + redgA[g][3];
    const float score = sumv - 2.f * Plds[g][s];

    {
        float wm = wave_red_max(score);
        if ((tid & 63) == 0) redgB[g][wig] = wm;
    }
    __syncthreads();
    const float mx = fmaxf(fmaxf(redgB[g][0], redgB[g][1]), fmaxf(redgB[g][2], redgB[g][3]));
    const float e = __expf(score - mx);
    {
        float ws = wave_red_sum(e);
        if ((tid & 63) == 0) redgA[g][wig] = ws;
    }
    __syncthreads();
    const float sE = redgA[g][0] + redgA[g][1] + redgA[g][2] + redgA[g][3];
    const float mq = (e / sE) * (float)mask[b * SRC + s];
    {
        float ws = wave_red_sum(mq);
        if ((tid & 63) == 0) redgB[g][wig] = ws;
    }
    __syncthreads();
    const float sM = redgB[g][0] + redgB[g][1] + redgB[g][2] + redgB[g][3];
    const float p = mq / (sM + 1e-12f);
    __syncthreads();
    Plds[g][s] = p;
    probs_out[((size_t)(b * TGT + t0 + g)) * SRC + s] = p;
    __syncthreads();

    // ---- context: dg = tid>>9 handles rows {2dg, 2dg+1}; d = tid&511 ----
    const int dg = tid >> 9;
    const int d  = tid & 511;
    const float* __restrict__ encb = enc + (size_t)b * SRC * TSD + d;
    float c0 = 0.f, c1 = 0.f;
    #pragma unroll 4
    for (int s2 = 0; s2 < SRC; ++s2) {
        const float ev = encb[(size_t)s2 * TSD];
        c0 = fmaf(Plds[2 * dg + 0][s2], ev, c0);
        c1 = fmaf(Plds[2 * dg + 1][s2], ev, c1);
    }
    ctx_out[((size_t)(b * TGT + t0 + 2 * dg + 0)) * TSD + d] = c0;
    ctx_out[((size_t)(b * TGT + t0 + 2 * dg + 1)) * TSD + d] = c1;
}

extern "C" void kernel_launch(void* const* d_in, const int* in_sizes, int n_in,
                              void* d_out, int out_size, void* d_ws, size_t ws_size,
                              hipStream_t stream) {
    const float* hid  = (const float*)d_in[0];   // (4,256,512)
    const float* enc  = (const float*)d_in[1];   // (4,256,512)
    const int*   mask = (const int*)  d_in[2];   // (4,256)
    const float* W    = (const float*)d_in[3];   // (512,1024)
    const float* bias = (const float*)d_in[4];   // (512,)
    const float* v    = (const float*)d_in[5];   // (512,)

    float* out   = (float*)d_out;
    float* ctx   = out;                       // 4*256*512
    float* probs = out + NB * TGT * TSD;      // 4*256*256

    float* hpE2 = (float*)d_ws;               // 1024*512: S*exp2(K*h)/v    2 MB
    float* epE  = hpE2 + NB * TGT * TSD;      // 4*512*256: exp2(K*(e+b))^T 2 MB

    dim3 pb(16, 16);
    dim3 pg(TSD / 64, (NB * TGT) / 64, 2);
    proj_kernel<<<pg, pb, 0, stream>>>(hid, enc, W, bias, v, hpE2, epE);

    dim3 ag(TGT / 4, NB);
    attn_fused_kernel<<<ag, 1024, 0, stream>>>(hpE2, epE, v, mask, enc, ctx, probs);
}